// Round 5
// baseline (132.214 us; speedup 1.0000x reference)
//
#include <hip/hip_runtime.h>

#define NHEAD 4
#define NNODE 4096
#define DIM 256
#define ROWS 32
#define CT 64
#define NT (NNODE / CT)
#define NEGV (-9e15f)

typedef float        f32x4  __attribute__((ext_vector_type(4)));
typedef int          i32x4  __attribute__((ext_vector_type(4)));
typedef unsigned int u32x2  __attribute__((ext_vector_type(2)));
typedef unsigned int u32x4  __attribute__((ext_vector_type(4)));
typedef short        bf16x8 __attribute__((ext_vector_type(8)));
typedef float        f32x16 __attribute__((ext_vector_type(16)));

__device__ __forceinline__ unsigned int f2bf(float f) {
  unsigned int u = __float_as_uint(f);
  u += 0x7fffu + ((u >> 16) & 1u);   // RNE to bf16
  return u >> 16;
}

// ---- fused pre-pass: blocks 0..255 build xF (B-frag-ordered bf16 x),
//      blocks 256..4351 build the adjacency bitmask. One parallel launch. ----
__global__ __launch_bounds__(256) void prep_all(const float* __restrict__ xg,
                                                const int* __restrict__ adj,
                                                unsigned short* __restrict__ xF,
                                                unsigned int* __restrict__ bits) {
  const int blk = blockIdx.x;
  const int t = threadIdx.x;
  if (blk < 256) {
    // xF chunk (h, it, ks, lhi, d) of 8 bf16: x[h][it*64+ks*16+lhi*8+j][d]
    __shared__ unsigned short tile[64 * 260];
    const int h = blk >> 6;
    const int it = blk & 63;
    const int n = t >> 2;
    const int dsg = (t & 3) << 6;
    const float* src = xg + ((size_t)h * NNODE + (it << 6) + n) * DIM + dsg;
#pragma unroll
    for (int j = 0; j < 16; ++j) {
      const f32x4 v = *(const f32x4*)(src + 4 * j);
      u32x2 w;
      w[0] = f2bf(v[0]) | (f2bf(v[1]) << 16);
      w[1] = f2bf(v[2]) | (f2bf(v[3]) << 16);
      *(u32x2*)&tile[n * 260 + dsg + 4 * j] = w;
    }
    __syncthreads();
    const int d = t;
    unsigned short* ob = xF + ((size_t)((h << 6) + it) * 2048 + d) * 8;
#pragma unroll
    for (int ks = 0; ks < 4; ++ks)
#pragma unroll
      for (int lh = 0; lh < 2; ++lh) {
        bf16x8 val;
#pragma unroll
        for (int j = 0; j < 8; ++j) val[j] = (short)tile[(ks * 16 + lh * 8 + j) * 260 + d];
        *(bf16x8*)(ob + (size_t)(ks * 2 + lh) * 256 * 8) = val;
      }
  } else {
    const int row = blk - 256;
    const int lane = t & 63, wv = t >> 6;
#pragma unroll
    for (int rep = 0; rep < 16; ++rep) {
      const int c = (rep << 8) + t;
      const unsigned long long m = __ballot(adj[(size_t)row * NNODE + c] > 0);
      if (lane == 0) {
        bits[row * 128 + (rep << 3) + (wv << 1)]     = (unsigned int)m;
        bits[row * 128 + (rep << 3) + (wv << 1) + 1] = (unsigned int)(m >> 32);
      }
    }
  }
}

// ---- main: shift-free softmax (P=exp(s), masked->0), P@X via MFMA ----
// att/bits depth-3 prefetch (~1350cy in flight > 900cy HBM latency);
// xF B-frags depth-2 (L2 hits, ~1.5 iters slack). Queue order per iter:
// [xf(it+1)] then [att/bits(it+3)] so draining xf(it) at the MFMA keeps
// att(it+2..3) outstanding. lgkm-only barrier; P double-buffered in LDS.
__global__ __launch_bounds__(512, 4) void gat_v4(
    const unsigned short* __restrict__ xF, const unsigned int* __restrict__ abits,
    const float* __restrict__ att, float* __restrict__ outg) {
  __shared__ unsigned short p_lds[2][ROWS * CT];   // 8 KB
  __shared__ float l_lds[ROWS];

  const int t = threadIdx.x;
  const int lane = t & 63;
  const int flat = blockIdx.x;
  const int xcd = flat & 7;                 // round-robin XCD dispatch
  const int h   = xcd >> 1;                 // head pinned to an XCD pair
  const int rb  = ((xcd & 1) << 6) | (flat >> 3);   // 0..127
  const int r0  = rb * ROWS;

  // score mapping: 16 threads/row, 4 cols each
  const int sr  = t >> 4;                   // 0..31
  const int c4  = (t & 15) << 2;            // 0..60
  const float* attb = att + ((size_t)h * NNODE + r0 + sr) * NNODE + c4;
  const unsigned int* ab = abits + (size_t)(r0 + sr) * 128 + (c4 >> 5);
  const int bsh = c4 & 31;

  // mfma mapping: wave -> 32-wide d slice
  const int wv   = t >> 6;
  const int d0   = wv << 5;
  const int lhi  = lane >> 5;
  const int lcol = lane & 31;
  const int axor = (lcol & 7) << 3;
  const unsigned short* xfb = xF + (size_t)h * NT * 16384 + ((lhi << 8) + d0 + lcol) * 8;

  f32x16 acc = {0.f};
  float psum = 0.f;

  // prologue: xf depth-1 (cur), att/bits depth-3
  bf16x8 xf0 = *(const bf16x8*)(xfb);
  bf16x8 xf1 = *(const bf16x8*)(xfb + 4096);
  bf16x8 xf2 = *(const bf16x8*)(xfb + 8192);
  bf16x8 xf3 = *(const bf16x8*)(xfb + 12288);
  f32x4 a0 = __builtin_nontemporal_load((const f32x4*)attb);
  f32x4 a1 = __builtin_nontemporal_load((const f32x4*)(attb + CT));
  f32x4 a2 = __builtin_nontemporal_load((const f32x4*)(attb + 2 * CT));
  unsigned int w0 = ab[0], w1 = ab[2], w2 = ab[4];

  int buf = 0;
  for (int it = 0; it < NT; ++it) {
    // 1. xf(it+1) prefetch (L2 hits; ~1.5 iters to land)
    const int itn = (it + 1) & (NT - 1);
    const unsigned short* xfi = xfb + (size_t)itn * 16384;
    const bf16x8 nx0 = *(const bf16x8*)(xfi);
    const bf16x8 nx1 = *(const bf16x8*)(xfi + 4096);
    const bf16x8 nx2 = *(const bf16x8*)(xfi + 8192);
    const bf16x8 nx3 = *(const bf16x8*)(xfi + 12288);

    // 2. att/bits(it+3) prefetch (youngest in queue -> survives xf drain)
    const int it3 = (it + 3) & (NT - 1);
    const f32x4 a3 = __builtin_nontemporal_load((const f32x4*)(attb + it3 * CT));
    const unsigned int w3 = ab[it3 << 1];

    // 3. P = exp(lrelu masked) — no max tracking (softmax shift-invariant)
    float e0, e1, e2, e3;
    {
      float s0 = a0[0], s1 = a0[1], s2 = a0[2], s3 = a0[3];
      s0 = fmaxf(s0, 0.2f * s0); s1 = fmaxf(s1, 0.2f * s1);
      s2 = fmaxf(s2, 0.2f * s2); s3 = fmaxf(s3, 0.2f * s3);
      s0 = ((w0 >> (bsh + 0)) & 1u) ? s0 : NEGV;
      s1 = ((w0 >> (bsh + 1)) & 1u) ? s1 : NEGV;
      s2 = ((w0 >> (bsh + 2)) & 1u) ? s2 : NEGV;
      s3 = ((w0 >> (bsh + 3)) & 1u) ? s3 : NEGV;
      e0 = __expf(s0); e1 = __expf(s1); e2 = __expf(s2); e3 = __expf(s3);
      psum += (e0 + e1) + (e2 + e3);
    }
    u32x2 pk;
    pk[0] = f2bf(e0) | (f2bf(e1) << 16);
    pk[1] = f2bf(e2) | (f2bf(e3) << 16);
    *(u32x2*)&p_lds[buf][sr * CT + (c4 ^ ((sr & 7) << 3))] = pk;

    // 4. own ds_write must land; global prefetches stay outstanding
    asm volatile("s_waitcnt lgkmcnt(0)" ::: "memory");
    __builtin_amdgcn_s_barrier();

    // 5. A-frags from LDS, MFMA with xf(it) regs
    const unsigned short* pr = &p_lds[buf][lcol * CT];
    const int mkb = lhi << 3;
    const bf16x8 A0 = *(const bf16x8*)&pr[(mkb +  0) ^ axor];
    const bf16x8 A1 = *(const bf16x8*)&pr[(mkb + 16) ^ axor];
    const bf16x8 A2 = *(const bf16x8*)&pr[(mkb + 32) ^ axor];
    const bf16x8 A3 = *(const bf16x8*)&pr[(mkb + 48) ^ axor];
    acc = __builtin_amdgcn_mfma_f32_32x32x16_bf16(A0, xf0, acc, 0, 0, 0);
    acc = __builtin_amdgcn_mfma_f32_32x32x16_bf16(A1, xf1, acc, 0, 0, 0);
    acc = __builtin_amdgcn_mfma_f32_32x32x16_bf16(A2, xf2, acc, 0, 0, 0);
    acc = __builtin_amdgcn_mfma_f32_32x32x16_bf16(A3, xf3, acc, 0, 0, 0);

    // 6. rotate pipeline registers
    a0 = a1; a1 = a2; a2 = a3;
    w0 = w1; w1 = w2; w2 = w3;
    xf0 = nx0; xf1 = nx1; xf2 = nx2; xf3 = nx3;
    buf ^= 1;
  }

  // ---- epilogue: reduce denominator once, normalize, store ----
  float l = psum;
  l += __shfl_xor(l, 1);
  l += __shfl_xor(l, 2);
  l += __shfl_xor(l, 4);
  l += __shfl_xor(l, 8);
  if ((t & 15) == 0) l_lds[sr] = l;
  __syncthreads();
  float* outb = outg + ((size_t)h * NNODE + r0) * DIM + d0 + lcol;
#pragma unroll
  for (int q = 0; q < 4; ++q) {
    const f32x4 lv = *(const f32x4*)&l_lds[q * 8 + lhi * 4];
    const int rbase = q * 8 + lhi * 4;   // C/D row = (reg&3)+8*(reg>>2)+4*(lane>>5)
#pragma unroll
    for (int i = 0; i < 4; ++i)
      __builtin_nontemporal_store(acc[q * 4 + i] / lv[i], outb + (size_t)(rbase + i) * DIM);
  }
}

// ---------- R1 kernel kept as fallback when ws is too small ----------
__global__ __launch_bounds__(512, 4) void gat_fused(
    const float* __restrict__ xg, const int* __restrict__ adj,
    const float* __restrict__ att, float* __restrict__ outg) {
  __shared__ __align__(16) unsigned short p_l[64 * 64];
  __shared__ __align__(16) unsigned short xT_l[DIM * 64];
  __shared__ __align__(16) float fac_l[64];
  __shared__ __align__(16) float ll_l[64];
  const int t = threadIdx.x;
  const int lane = t & 63;
  const int flat = blockIdx.x;
  const int xcd  = flat & 7;
  const int h    = xcd >> 1;
  const int rb   = ((xcd & 1) << 5) | (flat >> 3);
  const int r0   = rb * 64;
  const int srow = t >> 3;
  const int sm0  = (t & 7) << 3;
  const float* attb = att + ((size_t)h * NNODE + (r0 + srow)) * NNODE + sm0;
  const int*   adjb = adj + (size_t)(r0 + srow) * NNODE + sm0;
  const int xm0 = (t >> 5) << 2;
  const int xd0 = (t & 31) << 2;
  const float* xb_h = xg + (size_t)h * NNODE * DIM;
  const int wv   = t >> 6;
  const int d0   = wv << 5;
  const int lhi  = lane >> 5;
  const int lcol = lane & 31;
  f32x16 acc0 = {0.f};
  f32x16 acc1 = {0.f};
  float m_run = -__builtin_inff();
  float l_run = 0.f;
  for (int it = 0; it < 64; ++it) {
    const int c0 = it * 64;
    {
      const f32x4 A0 = __builtin_nontemporal_load((const f32x4*)(attb + c0));
      const f32x4 A1 = __builtin_nontemporal_load((const f32x4*)(attb + c0) + 1);
      const i32x4 j0 = *((const i32x4*)(adjb + c0));
      const i32x4 j1 = *((const i32x4*)(adjb + c0) + 1);
      float sv[8];
      int   av[8];
#pragma unroll
      for (int k = 0; k < 4; ++k) { sv[k] = A0[k]; sv[4 + k] = A1[k]; av[k] = j0[k]; av[4 + k] = j1[k]; }
#pragma unroll
      for (int k = 0; k < 8; ++k) {
        float s = sv[k];
        s = s > 0.f ? s : 0.2f * s;
        sv[k] = (av[k] > 0) ? s : NEGV;
      }
      float tmax = sv[0];
#pragma unroll
      for (int k = 1; k < 8; ++k) tmax = fmaxf(tmax, sv[k]);
      tmax = fmaxf(tmax, __shfl_xor(tmax, 1));
      tmax = fmaxf(tmax, __shfl_xor(tmax, 2));
      tmax = fmaxf(tmax, __shfl_xor(tmax, 4));
      const float m_new = fmaxf(m_run, tmax);
      float ps = 0.f;
#pragma unroll
      for (int k = 0; k < 8; ++k) { sv[k] = __expf(sv[k] - m_new); ps += sv[k]; }
      ps += __shfl_xor(ps, 1);
      ps += __shfl_xor(ps, 2);
      ps += __shfl_xor(ps, 4);
      const float fac = __expf(m_run - m_new);
      l_run = l_run * fac + ps;
      m_run = m_new;
      if ((t & 7) == 0) fac_l[srow] = fac;
      u32x4 pk;
      pk[0] = f2bf(sv[0]) | (f2bf(sv[1]) << 16);
      pk[1] = f2bf(sv[2]) | (f2bf(sv[3]) << 16);
      pk[2] = f2bf(sv[4]) | (f2bf(sv[5]) << 16);
      pk[3] = f2bf(sv[6]) | (f2bf(sv[7]) << 16);
      *(u32x4*)&p_l[srow * 64 + (sm0 ^ ((srow & 7) << 3))] = pk;
    }
    {
      const float* xb = xb_h + (size_t)(c0 + xm0) * DIM;
#pragma unroll
      for (int hh2 = 0; hh2 < 2; ++hh2) {
        const int dbase = xd0 + hh2 * 128;
        const f32x4 r0v = *(const f32x4*)(xb + dbase);
        const f32x4 r1v = *(const f32x4*)(xb + DIM + dbase);
        const f32x4 r2v = *(const f32x4*)(xb + 2 * DIM + dbase);
        const f32x4 r3v = *(const f32x4*)(xb + 3 * DIM + dbase);
#pragma unroll
        for (int j = 0; j < 4; ++j) {
          const int d = dbase + j;
          u32x2 wds;
          wds[0] = f2bf(r0v[j]) | (f2bf(r1v[j]) << 16);
          wds[1] = f2bf(r2v[j]) | (f2bf(r3v[j]) << 16);
          *(u32x2*)&xT_l[d * 64 + (xm0 ^ (((d >> 2) & 7) << 3))] = wds;
        }
      }
    }
    __syncthreads();
    {
#pragma unroll
      for (int q = 0; q < 4; ++q) {
        const f32x4 fa = *(const f32x4*)&fac_l[q * 8 + lhi * 4];
        const f32x4 fb = *(const f32x4*)&fac_l[32 + q * 8 + lhi * 4];
#pragma unroll
        for (int i = 0; i < 4; ++i) { acc0[q * 4 + i] *= fa[i]; acc1[q * 4 + i] *= fb[i]; }
      }
#pragma unroll
      for (int ks = 0; ks < 4; ++ks) {
        const int mk = ks * 16 + lhi * 8;
        const bf16x8 afA = *(const bf16x8*)&p_l[lcol * 64 + (mk ^ ((lcol & 7) << 3))];
        const bf16x8 afB = *(const bf16x8*)&p_l[(32 + lcol) * 64 + (mk ^ ((lcol & 7) << 3))];
        const int dd = d0 + lcol;
        const bf16x8 bfr = *(const bf16x8*)&xT_l[dd * 64 + (mk ^ (((dd >> 2) & 7) << 3))];
        acc0 = __builtin_amdgcn_mfma_f32_32x32x16_bf16(afA, bfr, acc0, 0, 0, 0);
        acc1 = __builtin_amdgcn_mfma_f32_32x32x16_bf16(afB, bfr, acc1, 0, 0, 0);
      }
    }
    __syncthreads();
  }
  if ((t & 7) == 0) ll_l[srow] = l_run;
  __syncthreads();
  float* outb = outg + (size_t)h * NNODE * DIM + (size_t)r0 * DIM + d0 + lcol;
#pragma unroll
  for (int q = 0; q < 4; ++q) {
    const f32x4 la = *(const f32x4*)&ll_l[q * 8 + lhi * 4];
    const f32x4 lb = *(const f32x4*)&ll_l[32 + q * 8 + lhi * 4];
    const int rbase = q * 8 + lhi * 4;
#pragma unroll
    for (int i = 0; i < 4; ++i) {
      __builtin_nontemporal_store(acc0[q * 4 + i] / la[i], outb + (size_t)(rbase + i) * DIM);
      __builtin_nontemporal_store(acc1[q * 4 + i] / lb[i], outb + (size_t)(32 + rbase + i) * DIM);
    }
  }
}

extern "C" void kernel_launch(void* const* d_in, const int* in_sizes, int n_in,
                              void* d_out, int out_size, void* d_ws, size_t ws_size,
                              hipStream_t stream) {
  const float* xg  = (const float*)d_in[0];
  const int*   adj = (const int*)d_in[1];
  const float* att = (const float*)d_in[2];
  float*       outg = (float*)d_out;
  const size_t xf_bytes = (size_t)NHEAD * DIM * NNODE * 2;   // 8 MB
  const size_t ab_bytes = (size_t)NNODE * 128 * 4;           // 2 MB
  if (ws_size >= xf_bytes + ab_bytes) {
    unsigned short* xF    = (unsigned short*)d_ws;
    unsigned int*   abits = (unsigned int*)((char*)d_ws + xf_bytes);
    prep_all<<<dim3(256 + NNODE), dim3(256), 0, stream>>>(xg, adj, xF, abits);
    gat_v4<<<dim3(512), dim3(512), 0, stream>>>(xF, abits, att, outg);
  } else {
    gat_fused<<<dim3(256), dim3(512), 0, stream>>>(xg, adj, att, outg);
  }
}